// Round 2
// baseline (247.791 us; speedup 1.0000x reference)
//
#include <hip/hip_runtime.h>

#define SEQ 4096
#define EMB 1024
#define HS 64
#define PCOLS 192   // packed QKV columns: [0,64)=q [64,128)=k [128,192)=v

typedef __attribute__((ext_vector_type(8))) short bf16x8;
typedef __attribute__((ext_vector_type(4))) float f32x4;

__device__ __forceinline__ unsigned short f2b(float f) {
    union { float f; unsigned u; } v; v.f = f;
    unsigned r = v.u + 0x7fffu + ((v.u >> 16) & 1u);
    return (unsigned short)(r >> 16);
}

// ---------- W transpose + cast: Wt[192][1024] bf16 ----------
__global__ __launch_bounds__(256) void wt_kernel(const float* __restrict__ Wq,
                                                 const float* __restrict__ Wk,
                                                 const float* __restrict__ Wv,
                                                 unsigned short* __restrict__ Wt) {
    int id = blockIdx.x * 256 + threadIdx.x;   // [0, 3*1024*64)
    int mat = id >> 16;
    int rem = id & 65535;
    int k = rem >> 6;
    int n = rem & 63;
    const float* W = (mat == 0) ? Wq : (mat == 1) ? Wk : Wv;
    Wt[(mat * HS + n) * EMB + k] = f2b(W[k * HS + n]);
}

// ---------- fused QKV projection: P[16384][192] bf16 ----------
#define LDA 72
__global__ __launch_bounds__(256) void proj_kernel(const float* __restrict__ x,
                                                   const unsigned short* __restrict__ Wt,
                                                   unsigned short* __restrict__ P) {
    __shared__ unsigned short A_lds[64 * LDA];
    const int tid = threadIdx.x;
    const int wave = tid >> 6, lane = tid & 63;
    const int col = lane & 15, quad = lane >> 4;
    const int m0 = blockIdx.x * 64;

    f32x4 acc[4][3];
    #pragma unroll
    for (int i = 0; i < 4; i++)
        #pragma unroll
        for (int j = 0; j < 3; j++) acc[i][j] = (f32x4){0.f, 0.f, 0.f, 0.f};

    for (int kt = 0; kt < EMB; kt += 64) {
        __syncthreads();
        #pragma unroll
        for (int i = 0; i < 4; i++) {
            int id = tid + i * 256;
            int row = id >> 4, c4 = id & 15;
            float4 v = *(const float4*)(x + (size_t)(m0 + row) * EMB + kt + c4 * 4);
            ushort4 bb;
            bb.x = f2b(v.x); bb.y = f2b(v.y); bb.z = f2b(v.z); bb.w = f2b(v.w);
            *(ushort4*)&A_lds[row * LDA + c4 * 4] = bb;
        }
        __syncthreads();
        bf16x8 af[4][2], bfr[3][2];
        #pragma unroll
        for (int mt = 0; mt < 4; mt++)
            #pragma unroll
            for (int c = 0; c < 2; c++)
                af[mt][c] = *(const bf16x8*)&A_lds[(mt * 16 + col) * LDA + quad * 8 + c * 32];
        #pragma unroll
        for (int nt = 0; nt < 3; nt++) {
            int n = wave * 48 + nt * 16 + col;
            #pragma unroll
            for (int c = 0; c < 2; c++)
                bfr[nt][c] = *(const bf16x8*)(Wt + (size_t)n * EMB + kt + quad * 8 + c * 32);
        }
        #pragma unroll
        for (int mt = 0; mt < 4; mt++)
            #pragma unroll
            for (int nt = 0; nt < 3; nt++)
                #pragma unroll
                for (int c = 0; c < 2; c++)
                    acc[mt][nt] = __builtin_amdgcn_mfma_f32_16x16x32_bf16(
                        af[mt][c], bfr[nt][c], acc[mt][nt], 0, 0, 0);
    }
    #pragma unroll
    for (int mt = 0; mt < 4; mt++)
        #pragma unroll
        for (int nt = 0; nt < 3; nt++) {
            int n = wave * 48 + nt * 16 + col;
            #pragma unroll
            for (int r = 0; r < 4; r++) {
                int row = m0 + mt * 16 + quad * 4 + r;
                P[(size_t)row * PCOLS + n] = f2b(acc[mt][nt][r]);
            }
        }
}

// ---------- flash attention (causal), BM=BN=64, 4 waves ----------
#define LDK 72
__global__ __launch_bounds__(256) void attn_kernel(const unsigned short* __restrict__ P,
                                                   float* __restrict__ out) {
    __shared__ unsigned short Q_lds[64 * LDK];
    __shared__ unsigned short K_lds[64 * LDK];
    __shared__ unsigned short V_lds[64 * LDK];      // transposed: [h][kv]
    __shared__ unsigned short P_lds[4][16 * LDK];   // per-wave P tile [16][72]

    const int tid = threadIdx.x;
    const int wave = tid >> 6, lane = tid & 63;
    const int col = lane & 15, quad = lane >> 4;
    const int qt = blockIdx.x & 63;
    const int b = blockIdx.x >> 6;
    const int q0 = qt * 64;
    const size_t prow0 = (size_t)b * SEQ;

    // stage Q (cols 0..63 of P)
    #pragma unroll
    for (int i = 0; i < 2; i++) {
        int id = tid + i * 256;
        int row = id >> 3, c8 = id & 7;
        uint4 v = *(const uint4*)(P + (prow0 + q0 + row) * PCOLS + c8 * 8);
        *(uint4*)&Q_lds[row * LDK + c8 * 8] = v;
    }
    __syncthreads();
    bf16x8 qf[2];
    #pragma unroll
    for (int c = 0; c < 2; c++)
        qf[c] = *(const bf16x8*)&Q_lds[(wave * 16 + col) * LDK + quad * 8 + c * 32];

    f32x4 o[4];
    float m_i[4], l_i[4];
    #pragma unroll
    for (int ct = 0; ct < 4; ct++) o[ct] = (f32x4){0.f, 0.f, 0.f, 0.f};
    #pragma unroll
    for (int r = 0; r < 4; r++) { m_i[r] = -1e30f; l_i[r] = 0.f; }

    for (int s = 0; s <= qt; s++) {
        const int kv0 = s * 64;
        __syncthreads();
        // stage K (cols 64..127)
        #pragma unroll
        for (int i = 0; i < 2; i++) {
            int id = tid + i * 256;
            int row = id >> 3, c8 = id & 7;
            uint4 v = *(const uint4*)(P + (prow0 + kv0 + row) * PCOLS + 64 + c8 * 8);
            *(uint4*)&K_lds[row * LDK + c8 * 8] = v;
        }
        // stage V transposed (cols 128..191)
        #pragma unroll
        for (int i = 0; i < 4; i++) {
            int id = tid + i * 256;
            int row = id >> 4, c4 = id & 15;
            ushort4 v = *(const ushort4*)(P + (prow0 + kv0 + row) * PCOLS + 128 + c4 * 4);
            V_lds[(c4 * 4 + 0) * LDK + row] = v.x;
            V_lds[(c4 * 4 + 1) * LDK + row] = v.y;
            V_lds[(c4 * 4 + 2) * LDK + row] = v.z;
            V_lds[(c4 * 4 + 3) * LDK + row] = v.w;
        }
        __syncthreads();

        // S = Q K^T  (16 rows/wave x 64 cols)
        f32x4 sacc[4];
        #pragma unroll
        for (int ct = 0; ct < 4; ct++) sacc[ct] = (f32x4){0.f, 0.f, 0.f, 0.f};
        #pragma unroll
        for (int ct = 0; ct < 4; ct++)
            #pragma unroll
            for (int c = 0; c < 2; c++) {
                bf16x8 kf = *(const bf16x8*)&K_lds[(ct * 16 + col) * LDK + quad * 8 + c * 32];
                sacc[ct] = __builtin_amdgcn_mfma_f32_16x16x32_bf16(qf[c], kf, sacc[ct], 0, 0, 0);
            }

        float sc[4][4];
        #pragma unroll
        for (int ct = 0; ct < 4; ct++)
            #pragma unroll
            for (int r = 0; r < 4; r++) sc[ct][r] = sacc[ct][r] * 0.125f;

        if (s == qt) {  // diagonal tile: causal mask
            #pragma unroll
            for (int ct = 0; ct < 4; ct++) {
                int cg = kv0 + ct * 16 + col;
                #pragma unroll
                for (int r = 0; r < 4; r++) {
                    int rg = q0 + wave * 16 + quad * 4 + r;
                    if (cg > rg) sc[ct][r] = -1e30f;
                }
            }
        }

        // row max over 64 cols: local over ct, then 16-lane (quad-group) butterfly
        float rmax[4];
        #pragma unroll
        for (int r = 0; r < 4; r++)
            rmax[r] = fmaxf(fmaxf(sc[0][r], sc[1][r]), fmaxf(sc[2][r], sc[3][r]));
        #pragma unroll
        for (int off = 1; off < 16; off <<= 1)
            #pragma unroll
            for (int r = 0; r < 4; r++)
                rmax[r] = fmaxf(rmax[r], __shfl_xor(rmax[r], off, 64));

        float mnew[4], alpha[4];
        #pragma unroll
        for (int r = 0; r < 4; r++) {
            mnew[r] = fmaxf(m_i[r], rmax[r]);
            alpha[r] = __expf(m_i[r] - mnew[r]);
            m_i[r] = mnew[r];
        }
        float p[4][4], rsum[4];
        #pragma unroll
        for (int r = 0; r < 4; r++) rsum[r] = 0.f;
        #pragma unroll
        for (int ct = 0; ct < 4; ct++)
            #pragma unroll
            for (int r = 0; r < 4; r++) {
                p[ct][r] = __expf(sc[ct][r] - mnew[r]);
                rsum[r] += p[ct][r];
            }
        #pragma unroll
        for (int off = 1; off < 16; off <<= 1)
            #pragma unroll
            for (int r = 0; r < 4; r++)
                rsum[r] += __shfl_xor(rsum[r], off, 64);
        #pragma unroll
        for (int r = 0; r < 4; r++) l_i[r] = l_i[r] * alpha[r] + rsum[r];
        #pragma unroll
        for (int ct = 0; ct < 4; ct++)
            #pragma unroll
            for (int r = 0; r < 4; r++) o[ct][r] *= alpha[r];

        // P tile: C-layout -> LDS -> A-layout
        #pragma unroll
        for (int ct = 0; ct < 4; ct++)
            #pragma unroll
            for (int r = 0; r < 4; r++)
                P_lds[wave][(quad * 4 + r) * LDK + ct * 16 + col] = f2b(p[ct][r]);
        __syncthreads();

        bf16x8 pf[2];
        #pragma unroll
        for (int c = 0; c < 2; c++)
            pf[c] = *(const bf16x8*)&P_lds[wave][col * LDK + quad * 8 + c * 32];
        #pragma unroll
        for (int ct = 0; ct < 4; ct++)
            #pragma unroll
            for (int c = 0; c < 2; c++) {
                bf16x8 vf = *(const bf16x8*)&V_lds[(ct * 16 + col) * LDK + quad * 8 + c * 32];
                o[ct] = __builtin_amdgcn_mfma_f32_16x16x32_bf16(pf[c], vf, o[ct], 0, 0, 0);
            }
    }

    #pragma unroll
    for (int ct = 0; ct < 4; ct++)
        #pragma unroll
        for (int r = 0; r < 4; r++) {
            int t = q0 + wave * 16 + quad * 4 + r;
            out[((size_t)b * SEQ + t) * HS + ct * 16 + col] = o[ct][r] / l_i[r];
        }
}

extern "C" void kernel_launch(void* const* d_in, const int* in_sizes, int n_in,
                              void* d_out, int out_size, void* d_ws, size_t ws_size,
                              hipStream_t stream) {
    const float* x  = (const float*)d_in[0];
    const float* Wk = (const float*)d_in[1];
    const float* Wq = (const float*)d_in[2];
    const float* Wv = (const float*)d_in[3];
    float* out = (float*)d_out;

    unsigned short* Wt = (unsigned short*)d_ws;                       // 192*1024*2 = 393216 B
    unsigned short* P  = (unsigned short*)((char*)d_ws + 393216);     // 16384*192*2 = 6291456 B

    wt_kernel<<<dim3(768), dim3(256), 0, stream>>>(Wq, Wk, Wv, Wt);
    proj_kernel<<<dim3(256), dim3(256), 0, stream>>>(x, Wt, P);
    attn_kernel<<<dim3(256), dim3(256), 0, stream>>>(P, out);
}